// Round 14
// baseline (442.292 us; speedup 1.0000x reference)
//
#include <hip/hip_runtime.h>
#include <math.h>

#define NB 8
#define IN_CH 2
#define OUT_CHN 4
#define NSINC 4
#define CONDC 32
#define KK 256
#define HOP 64
#define TT 65536
#define NF 1025
#define LL (HOP*(NF-1)+KK)   /* 65792 */
#define PI_F 3.14159265358979323846f

/* ws layout (floats):
   wtab   @ 0       : 98304  (3 bf16 matrices x 65536 ushort, FRAGMENT layout)
   par    @ 98304   : 524800
   X      @ 623104  : 4198400
   acc    @ 4821504 : 2105344
   h_part @ 6926848 : 1049600
   total 7,976,448 floats = 31.9 MB */
#define WTAB_OFF 0
#define PAR_OFF  98304
#define X_OFF    623104
#define ACC_OFF  4821504
#define ACC_N    2105344
#define HPART_OFF 6926848

#define FPAD 264

typedef __attribute__((ext_vector_type(8))) short bf16x8;
typedef __attribute__((ext_vector_type(4))) float f32x4;

__device__ __forceinline__ void splitbf(float v, unsigned short& hi, unsigned short& lo) {
    unsigned bits = __float_as_uint(v);
    hi = (unsigned short)(bits >> 16);
    float r = v - __uint_as_float(bits & 0xffff0000u);
    lo = (unsigned short)(__float_as_uint(r) >> 16);
}

__device__ __forceinline__ unsigned short tobf16_rn(float v) {
    unsigned b = __float_as_uint(v);
    return (unsigned short)((b + 0x7FFFu + ((b >> 16) & 1u)) >> 16);
}

__device__ __forceinline__ float frombf16(unsigned short u) {
    return __uint_as_float(((unsigned)u) << 16);
}

/* sinc(x)=sin(pi x)/(pi x) via Taylor in (pi x)^2; |pi x| <= 1.571 here -> err < 4e-8 */
__device__ __forceinline__ float sincpoly(float x) {
    float y = PI_F * x;
    float y2 = y * y;
    return 1.f + y2 * (-1.6666667e-1f + y2 * (8.3333333e-3f + y2 * (-1.9841270e-4f
              + y2 * (2.7557319e-6f + y2 * (-2.5052108e-8f)))));
}

/* ---- W tables in MFMA B-FRAGMENT layout (verified R10):
   addr = (m<<16) | (nt<<12) | (ks<<9) | (koct<<7) | (sel<<3) | e ---- */
__global__ __launch_bounds__(256) void k_wsetup(unsigned short* __restrict__ wtab) {
    int idx = blockIdx.x * 256 + threadIdx.x;   /* grid 768 */
    int m = idx >> 16;
    int rem = idx & 65535;
    int oc = rem >> 8;
    int kd = rem & 255;
    const float ang = 2.f * PI_F / 256.f;
    float v;
    if (m < 2) {
        if (oc == 0) v = 1.f;
        else if (oc == 1) v = (kd & 1) ? -1.f : 1.f;
        else {
            int nu = oc >> 1;
            float th = ang * (float)((nu * kd) & 255);
            v = (oc & 1) ? -sinf(th) : cosf(th);
        }
        if (m == 0) v *= 0.5f * (1.f - cosf(ang * (float)kd));
    } else {
        float s;
        if (kd == 0) s = 1.f;
        else if (kd == 1) s = (oc & 1) ? -1.f : 1.f;
        else {
            int nu = kd >> 1;
            float th = ang * (float)((nu * oc) & 255);
            s = (kd & 1) ? -2.f * sinf(th) : 2.f * cosf(th);
        }
        v = s * (1.f / 256.f) * 0.5f * (1.f - cosf(ang * (float)oc));
    }
    int nt = oc >> 4, sel = oc & 15;
    int ks = kd >> 5, koct = (kd >> 3) & 3, e = kd & 7;
    wtab[(m << 16) | (nt << 12) | (ks << 9) | (koct << 7) | (sel << 3) | e] = tobf16_rn(v);
}

/* ---- hconv as split-bf16 MFMA GEMM (verified R4, unchanged) ---- */
__global__ __launch_bounds__(256) void k_hconv3(const float* __restrict__ cond,
                                                const float* __restrict__ w1,
                                                float* __restrict__ h_part) {
    __shared__ __align__(16) unsigned short s_a_hi[4824];
    __shared__ __align__(16) unsigned short s_a_lo[4824];
    __shared__ __align__(16) unsigned short s_b_hi[32 * 264];
    __shared__ __align__(16) unsigned short s_b_lo[32 * 264];
    const int t = threadIdx.x;
    const int ftile = blockIdx.x;
    const int g = blockIdx.y;
    const int b = blockIdx.z;
    const int f0 = ftile * 64;
    const long pos0 = (long)f0 * HOP - 128;
    const int w = t >> 6;
    const int l = t & 63;
    const int sel16 = l & 15;
    const int koct = l >> 4;

    f32x4 acc0 = {0.f, 0.f, 0.f, 0.f};
    f32x4 acc1 = {0.f, 0.f, 0.f, 0.f};

    for (int ci = 0; ci < 8; ++ci) {
        const int cin = g * 8 + ci;
        __syncthreads();
        const float* crow = &cond[((long)b * CONDC + cin) * TT];
        for (int u = t; u < 4288; u += 256) {
            long p = pos0 + u;
            if (p < 0) p = -p;
            if (p >= TT) p = 2 * (TT - 1) - p;
            unsigned short hi, lo;
            splitbf(crow[p], hi, lo);
            int off = u + ((u >> 6) << 3);
            s_a_hi[off] = hi;
            s_a_lo[off] = lo;
        }
        for (int m4 = t; m4 < 2048; m4 += 256) {
            int c = m4 >> 6;
            int k4 = (m4 & 63) << 2;
            float4 v = *(const float4*)&w1[((c * CONDC + cin) << 8) + k4];
            ushort4 hi, lo;
            splitbf(v.x, hi.x, lo.x);
            splitbf(v.y, hi.y, lo.y);
            splitbf(v.z, hi.z, lo.z);
            splitbf(v.w, hi.w, lo.w);
            int off = c * 264 + k4;
            *(ushort4*)&s_b_hi[off] = hi;
            *(ushort4*)&s_b_lo[off] = lo;
        }
        __syncthreads();
        const int flocal = w * 16 + sel16;
        #pragma unroll
        for (int ks = 0; ks < 8; ++ks) {
            int u = flocal * 64 + ks * 32 + koct * 8;
            int aoff = u + ((u >> 6) << 3);
            bf16x8 ahi = *(const bf16x8*)&s_a_hi[aoff];
            bf16x8 alo = *(const bf16x8*)&s_a_lo[aoff];
            int boff0 = sel16 * 264 + ks * 32 + koct * 8;
            int boff1 = (16 + sel16) * 264 + ks * 32 + koct * 8;
            bf16x8 b0h = *(const bf16x8*)&s_b_hi[boff0];
            bf16x8 b0l = *(const bf16x8*)&s_b_lo[boff0];
            bf16x8 b1h = *(const bf16x8*)&s_b_hi[boff1];
            bf16x8 b1l = *(const bf16x8*)&s_b_lo[boff1];
            acc0 = __builtin_amdgcn_mfma_f32_16x16x32_bf16(ahi, b0h, acc0, 0, 0, 0);
            acc0 = __builtin_amdgcn_mfma_f32_16x16x32_bf16(alo, b0h, acc0, 0, 0, 0);
            acc0 = __builtin_amdgcn_mfma_f32_16x16x32_bf16(ahi, b0l, acc0, 0, 0, 0);
            acc1 = __builtin_amdgcn_mfma_f32_16x16x32_bf16(ahi, b1h, acc1, 0, 0, 0);
            acc1 = __builtin_amdgcn_mfma_f32_16x16x32_bf16(alo, b1h, acc1, 0, 0, 0);
            acc1 = __builtin_amdgcn_mfma_f32_16x16x32_bf16(ahi, b1l, acc1, 0, 0, 0);
        }
    }

    #pragma unroll
    for (int j = 0; j < 4; ++j) {
        int f = f0 + w * 16 + koct * 4 + j;
        if (f < NF) {
            long base = (((long)g * NB + b) * NF + f) * CONDC;
            h_part[base + sel16] = acc0[j];
            h_part[base + 16 + sel16] = acc1[j];
        }
    }
}

__global__ __launch_bounds__(64) void k_params(const float* __restrict__ h_part,
                                               const float* __restrict__ w2,
                                               const float* __restrict__ b1,
                                               const float* __restrict__ b2,
                                               float* __restrict__ par) {
    __shared__ float s_h[CONDC];
    const int f = blockIdx.x;
    const int b = blockIdx.y;
    const int t = threadIdx.x;
    if (t < CONDC) {
        float v = b1[t];
        #pragma unroll
        for (int g = 0; g < 4; ++g)
            v += h_part[(((long)g * NB + b) * NF + f) * CONDC + t];
        s_h[t] = (v >= 0.f) ? v : 0.01f * v;
    }
    __syncthreads();
    float acc = b2[t];
    #pragma unroll 8
    for (int cin = 0; cin < CONDC; ++cin) acc += s_h[cin] * w2[t * CONDC + cin];
    par[((long)b * NF + f) * 64 + t] = tanhf(acc);
}

/* ---- forward DFT of windowed frames; W frags direct from global (verified R10) ---- */
__global__ __launch_bounds__(256) void k_dft_frames2(const float* __restrict__ x,
                                                     const unsigned short* __restrict__ wtab,
                                                     float* __restrict__ X) {
    __shared__ __align__(16) unsigned short s_a[4824];
    const int t = threadIdx.x;
    const int ftile = blockIdx.x;   /* 0..16 */
    const int bi = blockIdx.y;      /* 0..15 */
    const int f0 = ftile * 64;
    const long pos0 = (long)f0 * HOP - 128;
    const int w = t >> 6;
    const int l = t & 63;
    const int sel16 = l & 15;
    const int koct = l >> 4;

    const float* xrow = &x[(long)bi * TT];
    for (int u = t; u < 4288; u += 256) {
        long p = pos0 + u;
        if (p < 0) p = -p;
        if (p >= TT) p = 2 * (TT - 1) - p;
        int off = u + ((u >> 6) << 3);
        s_a[off] = tobf16_rn(xrow[p]);
    }
    __syncthreads();

    const unsigned short* WF = wtab + (l << 3);
    for (int nt = 0; nt < 16; ++nt) {
        f32x4 acc = {0.f, 0.f, 0.f, 0.f};
        #pragma unroll
        for (int ks = 0; ks < 8; ++ks) {
            int u = (w * 16 + sel16) * 64 + ks * 32 + koct * 8;
            int aoff = u + ((u >> 6) << 3);
            bf16x8 ah = *(const bf16x8*)&s_a[aoff];
            bf16x8 bh = *(const bf16x8*)&WF[(nt << 12) + (ks << 9)];
            acc = __builtin_amdgcn_mfma_f32_16x16x32_bf16(ah, bh, acc, 0, 0, 0);
        }
        #pragma unroll
        for (int j = 0; j < 4; ++j) {
            int f = f0 + w * 16 + koct * 4 + j;
            if (f < NF) X[((long)bi * NF + f) * 256 + nt * 16 + sel16] = acc[j];
        }
    }
}

/* ---- FUSED v5: R13 structure with VGPR capped for full occupancy.
   512 threads / 8 waves; __launch_bounds__(512,8) targets <=64 VGPR so
   LDS (35.8 KB) allows 4 blocks/CU = 32 waves/CU. X loaded inline (TLP hides). ---- */
__global__ __launch_bounds__(512, 8) void k_fused4(const float* __restrict__ par,
                                                   const unsigned short* __restrict__ wtab,
                                                   const float* __restrict__ X,
                                                   float* __restrict__ accb) {
    __shared__ __align__(16) unsigned short s_f[32 * FPAD];   /* 16.9 KB */
    __shared__ __align__(16) unsigned short s_y[32 * FPAD];   /* 16.9 KB */
    __shared__ float s_parl[512];                              /* 2 KB */
    float* s_ola = (float*)s_f;   /* iDFT-phase alias: 2240 f32 < 16.9 KB */

    const int t = threadIdx.x;      /* 0..511 */
    const int ftile = blockIdx.x;   /* 0..32 */
    const int bo = blockIdx.y;      /* 0..31 */
    const int b = bo >> 2;
    const int o = bo & 3;
    const int f0 = ftile * 32;
    const int w = t >> 6;           /* 0..7 */
    const int l = t & 63;
    const int sel16 = l & 15;
    const int koct = l >> 4;
    const int rh = w & 1;
    const int nh = w >> 1;          /* 0..3 */
    const int flocal = rh * 16 + sel16;
    const int kc = t & 255;         /* filt-build column */
    const int rhb = t >> 8;         /* filt-build row parity */

    const float ang = 2.f * PI_F / 256.f;
    const float ta = ((float)kc - 128.f) * (1.f / 256.f);
    const float fir = 0.42f - 0.5f * cosf(ang * (float)kc) + 0.08f * cosf(2.f * ang * (float)kc);
    const float fsc = fir * (1.f / 1024.f);

    const unsigned short* W0 = wtab + 65536 + (l << 3);
    const unsigned short* WI = wtab + 2 * 65536 + (l << 3);

    /* stage par: s_parl[f_r*16 + isel*8 + q], one element per thread */
    {
        int u = t;
        int f_r = u >> 4;
        int idx = u & 15;
        int isel = idx >> 3;
        int q = idx & 7;
        int col = (o * 2 + isel) * 4 + (q & 3) + ((q >> 2) * 32);
        int fc = f0 + f_r;
        if (fc >= NF) fc = NF - 1;
        s_parl[u] = par[((long)b * NF + fc) * 64 + col];
    }

    for (int i = 0; i < 2; ++i) {
        __syncthreads();   /* parl ready / prev-i s_f reads done */
        /* build filt tile: thread owns column kc, rows {rhb, rhb+2, ...} */
        for (int ri = 0; ri < 16; ++ri) {
            int r = ri * 2 + rhb;
            const float* pp = &s_parl[r * 16 + i * 8];
            float v = (pp[0] * sincpoly(pp[4] * ta + 1e-6f)
                     + pp[1] * sincpoly(pp[5] * ta + 1e-6f)
                     + pp[2] * sincpoly(pp[6] * ta + 1e-6f)
                     + pp[3] * sincpoly(pp[7] * ta + 1e-6f)) * fsc;
            s_f[r * FPAD + kc] = tobf16_rn(v);
        }
        __syncthreads();   /* filt ready */
        const long xbase = ((long)(b * 2 + i) * NF) * 256;
        for (int s = 0; s < 4; ++s) {
            const int nt = nh * 4 + s;
            f32x4 acc = {0.f, 0.f, 0.f, 0.f};
            #pragma unroll
            for (int ks = 0; ks < 8; ++ks) {
                bf16x8 ah = *(const bf16x8*)&s_f[flocal * FPAD + ks * 32 + koct * 8];
                bf16x8 bh = *(const bf16x8*)&W0[(nt << 12) + (ks << 9)];
                acc = __builtin_amdgcn_mfma_f32_16x16x32_bf16(ah, bh, acc, 0, 0, 0);
            }
            #pragma unroll
            for (int j = 0; j < 4; ++j) {
                int row = rh * 16 + koct * 4 + j;
                int col = nt * 16 + sel16;
                int f = f0 + row;
                float xv = (f < NF) ? X[xbase + (long)f * 256 + col] : 0.f;
                float h = acc[j];
                float p = h * xv;
                float q2 = __shfl_xor(p, 1);
                float r2 = h * __shfl_xor(xv, 1);
                float s2 = __shfl_xor(r2, 1);
                float yv = (sel16 & 1) ? (r2 + s2) : (p - q2);
                if (nt == 0 && sel16 < 2) yv = p;
                int yoff = row * FPAD + col;
                if (i == 0) s_y[yoff] = tobf16_rn(yv);
                else        s_y[yoff] = tobf16_rn(yv + frombf16(s_y[yoff]));
            }
        }
    }

    /* ---- phase 2: inverse DFT from s_y, OLA in LDS ---- */
    __syncthreads();   /* s_y complete; s_f reads done -> alias s_ola */
    for (int u = t; u < 2240; u += 512) s_ola[u] = 0.f;
    __syncthreads();
    for (int s = 0; s < 4; ++s) {
        const int nt = nh * 4 + s;
        f32x4 acc = {0.f, 0.f, 0.f, 0.f};
        #pragma unroll
        for (int ks = 0; ks < 8; ++ks) {
            bf16x8 ah = *(const bf16x8*)&s_y[flocal * FPAD + ks * 32 + koct * 8];
            bf16x8 bh = *(const bf16x8*)&WI[(nt << 12) + (ks << 9)];
            acc = __builtin_amdgcn_mfma_f32_16x16x32_bf16(ah, bh, acc, 0, 0, 0);
        }
        #pragma unroll
        for (int j = 0; j < 4; ++j) {
            int row = rh * 16 + koct * 4 + j;
            int n = nt * 16 + sel16;
            atomicAdd(&s_ola[row * 64 + n], acc[j]);
        }
    }
    __syncthreads();
    for (int u = t; u < 2240; u += 512) {
        long pos = (long)f0 * HOP + u;
        if (pos < (long)LL) {
            float v = s_ola[u];
            long base = ((long)(b * OUT_CHN + o)) * LL + pos;
            if (u < 192 || u >= 2048) atomicAdd(&accb[base], v);
            else accb[base] = v;
        }
    }
}

__global__ __launch_bounds__(256) void k_norm(const float* __restrict__ accbuf,
                                              const float* __restrict__ bias,
                                              float* __restrict__ out) {
    int idx = blockIdx.x * 256 + threadIdx.x;
    if (idx >= NB * OUT_CHN * TT) return;
    int tpos = idx & (TT - 1);
    int bo = idx >> 16;
    int o = bo & 3;
    int tt = tpos + 128;
    float env;
    if (tt >= 192 && tt < (NF - 1) * HOP) {
        env = 1.5f;   /* interior: sum of 4 overlapping hann^2 at hop=K/4 is exactly 3/2 */
    } else {
        env = 0.f;
        int fhi = tt >> 6;
        #pragma unroll
        for (int d = 0; d < 4; ++d) {
            int f = fhi - d;
            int n = tt - f * HOP;
            if (f >= 0 && f < NF && n >= 0 && n < KK) {
                float angn = (2.f * PI_F / 256.f) * (float)n;
                float wv = 0.5f * (1.f - cosf(angn));
                env += wv * wv;
            }
        }
    }
    out[idx] = accbuf[(long)bo * LL + tt] / env + bias[o];
}

extern "C" void kernel_launch(void* const* d_in, const int* in_sizes, int n_in,
                              void* d_out, int out_size, void* d_ws, size_t ws_size,
                              hipStream_t stream) {
    const float* x    = (const float*)d_in[0];
    const float* cond = (const float*)d_in[1];
    const float* w1   = (const float*)d_in[2];
    const float* b1   = (const float*)d_in[3];
    const float* w2   = (const float*)d_in[4];
    const float* b2   = (const float*)d_in[5];
    const float* bias = (const float*)d_in[6];
    float* out = (float*)d_out;
    float* ws  = (float*)d_ws;
    unsigned short* wtab = (unsigned short*)(ws + WTAB_OFF);
    float* par    = ws + PAR_OFF;
    float* X      = ws + X_OFF;
    float* acc    = ws + ACC_OFF;
    float* h_part = ws + HPART_OFF;

    hipLaunchKernelGGL(k_wsetup, dim3(768), dim3(256), 0, stream, wtab);
    hipLaunchKernelGGL(k_hconv3, dim3(17, 4, NB), dim3(256), 0, stream, cond, w1, h_part);
    hipLaunchKernelGGL(k_params, dim3(NF, NB), dim3(64), 0, stream, h_part, w2, b1, b2, par);
    hipLaunchKernelGGL(k_dft_frames2, dim3(17, 16), dim3(256), 0, stream, x, wtab, X);
    (void)hipMemsetAsync(acc, 0, (size_t)ACC_N * sizeof(float), stream);
    hipLaunchKernelGGL(k_fused4, dim3(33, 32), dim3(512), 0, stream, par, wtab, X, acc);
    hipLaunchKernelGGL(k_norm, dim3(8192), dim3(256), 0, stream, acc, bias, out);
}

// Round 15
// 228.929 us; speedup vs baseline: 1.9320x; 1.9320x over previous
//
#include <hip/hip_runtime.h>
#include <math.h>

#define NB 8
#define IN_CH 2
#define OUT_CHN 4
#define NSINC 4
#define CONDC 32
#define KK 256
#define HOP 64
#define TT 65536
#define NF 1025
#define LL (HOP*(NF-1)+KK)   /* 65792 */
#define PI_F 3.14159265358979323846f

/* ws layout (floats):
   wtab   @ 0       : 98304  (3 bf16 matrices x 65536 ushort, FRAGMENT layout)
   par    @ 98304   : 524800
   X      @ 623104  : 4198400
   acc    @ 4821504 : 2105344
   h_part @ 6926848 : 1049600
   total 7,976,448 floats = 31.9 MB */
#define WTAB_OFF 0
#define PAR_OFF  98304
#define X_OFF    623104
#define ACC_OFF  4821504
#define ACC_N    2105344
#define HPART_OFF 6926848

#define FPAD 264

typedef __attribute__((ext_vector_type(8))) short bf16x8;
typedef __attribute__((ext_vector_type(4))) float f32x4;

__device__ __forceinline__ void splitbf(float v, unsigned short& hi, unsigned short& lo) {
    unsigned bits = __float_as_uint(v);
    hi = (unsigned short)(bits >> 16);
    float r = v - __uint_as_float(bits & 0xffff0000u);
    lo = (unsigned short)(__float_as_uint(r) >> 16);
}

__device__ __forceinline__ unsigned short tobf16_rn(float v) {
    unsigned b = __float_as_uint(v);
    return (unsigned short)((b + 0x7FFFu + ((b >> 16) & 1u)) >> 16);
}

__device__ __forceinline__ float frombf16(unsigned short u) {
    return __uint_as_float(((unsigned)u) << 16);
}

/* sinc(x)=sin(pi x)/(pi x) via Taylor in (pi x)^2; |pi x| <= 1.571 here -> err < 4e-8 */
__device__ __forceinline__ float sincpoly(float x) {
    float y = PI_F * x;
    float y2 = y * y;
    return 1.f + y2 * (-1.6666667e-1f + y2 * (8.3333333e-3f + y2 * (-1.9841270e-4f
              + y2 * (2.7557319e-6f + y2 * (-2.5052108e-8f)))));
}

/* ---- W tables in MFMA B-FRAGMENT layout (verified R10):
   addr = (m<<16) | (nt<<12) | (ks<<9) | (koct<<7) | (sel<<3) | e ---- */
__global__ __launch_bounds__(256) void k_wsetup(unsigned short* __restrict__ wtab) {
    int idx = blockIdx.x * 256 + threadIdx.x;   /* grid 768 */
    int m = idx >> 16;
    int rem = idx & 65535;
    int oc = rem >> 8;
    int kd = rem & 255;
    const float ang = 2.f * PI_F / 256.f;
    float v;
    if (m < 2) {
        if (oc == 0) v = 1.f;
        else if (oc == 1) v = (kd & 1) ? -1.f : 1.f;
        else {
            int nu = oc >> 1;
            float th = ang * (float)((nu * kd) & 255);
            v = (oc & 1) ? -sinf(th) : cosf(th);
        }
        if (m == 0) v *= 0.5f * (1.f - cosf(ang * (float)kd));
    } else {
        float s;
        if (kd == 0) s = 1.f;
        else if (kd == 1) s = (oc & 1) ? -1.f : 1.f;
        else {
            int nu = kd >> 1;
            float th = ang * (float)((nu * oc) & 255);
            s = (kd & 1) ? -2.f * sinf(th) : 2.f * cosf(th);
        }
        v = s * (1.f / 256.f) * 0.5f * (1.f - cosf(ang * (float)oc));
    }
    int nt = oc >> 4, sel = oc & 15;
    int ks = kd >> 5, koct = (kd >> 3) & 3, e = kd & 7;
    wtab[(m << 16) | (nt << 12) | (ks << 9) | (koct << 7) | (sel << 3) | e] = tobf16_rn(v);
}

/* ---- hconv as split-bf16 MFMA GEMM (verified R4, unchanged) ---- */
__global__ __launch_bounds__(256) void k_hconv3(const float* __restrict__ cond,
                                                const float* __restrict__ w1,
                                                float* __restrict__ h_part) {
    __shared__ __align__(16) unsigned short s_a_hi[4824];
    __shared__ __align__(16) unsigned short s_a_lo[4824];
    __shared__ __align__(16) unsigned short s_b_hi[32 * 264];
    __shared__ __align__(16) unsigned short s_b_lo[32 * 264];
    const int t = threadIdx.x;
    const int ftile = blockIdx.x;
    const int g = blockIdx.y;
    const int b = blockIdx.z;
    const int f0 = ftile * 64;
    const long pos0 = (long)f0 * HOP - 128;
    const int w = t >> 6;
    const int l = t & 63;
    const int sel16 = l & 15;
    const int koct = l >> 4;

    f32x4 acc0 = {0.f, 0.f, 0.f, 0.f};
    f32x4 acc1 = {0.f, 0.f, 0.f, 0.f};

    for (int ci = 0; ci < 8; ++ci) {
        const int cin = g * 8 + ci;
        __syncthreads();
        const float* crow = &cond[((long)b * CONDC + cin) * TT];
        for (int u = t; u < 4288; u += 256) {
            long p = pos0 + u;
            if (p < 0) p = -p;
            if (p >= TT) p = 2 * (TT - 1) - p;
            unsigned short hi, lo;
            splitbf(crow[p], hi, lo);
            int off = u + ((u >> 6) << 3);
            s_a_hi[off] = hi;
            s_a_lo[off] = lo;
        }
        for (int m4 = t; m4 < 2048; m4 += 256) {
            int c = m4 >> 6;
            int k4 = (m4 & 63) << 2;
            float4 v = *(const float4*)&w1[((c * CONDC + cin) << 8) + k4];
            ushort4 hi, lo;
            splitbf(v.x, hi.x, lo.x);
            splitbf(v.y, hi.y, lo.y);
            splitbf(v.z, hi.z, lo.z);
            splitbf(v.w, hi.w, lo.w);
            int off = c * 264 + k4;
            *(ushort4*)&s_b_hi[off] = hi;
            *(ushort4*)&s_b_lo[off] = lo;
        }
        __syncthreads();
        const int flocal = w * 16 + sel16;
        #pragma unroll
        for (int ks = 0; ks < 8; ++ks) {
            int u = flocal * 64 + ks * 32 + koct * 8;
            int aoff = u + ((u >> 6) << 3);
            bf16x8 ahi = *(const bf16x8*)&s_a_hi[aoff];
            bf16x8 alo = *(const bf16x8*)&s_a_lo[aoff];
            int boff0 = sel16 * 264 + ks * 32 + koct * 8;
            int boff1 = (16 + sel16) * 264 + ks * 32 + koct * 8;
            bf16x8 b0h = *(const bf16x8*)&s_b_hi[boff0];
            bf16x8 b0l = *(const bf16x8*)&s_b_lo[boff0];
            bf16x8 b1h = *(const bf16x8*)&s_b_hi[boff1];
            bf16x8 b1l = *(const bf16x8*)&s_b_lo[boff1];
            acc0 = __builtin_amdgcn_mfma_f32_16x16x32_bf16(ahi, b0h, acc0, 0, 0, 0);
            acc0 = __builtin_amdgcn_mfma_f32_16x16x32_bf16(alo, b0h, acc0, 0, 0, 0);
            acc0 = __builtin_amdgcn_mfma_f32_16x16x32_bf16(ahi, b0l, acc0, 0, 0, 0);
            acc1 = __builtin_amdgcn_mfma_f32_16x16x32_bf16(ahi, b1h, acc1, 0, 0, 0);
            acc1 = __builtin_amdgcn_mfma_f32_16x16x32_bf16(alo, b1h, acc1, 0, 0, 0);
            acc1 = __builtin_amdgcn_mfma_f32_16x16x32_bf16(ahi, b1l, acc1, 0, 0, 0);
        }
    }

    #pragma unroll
    for (int j = 0; j < 4; ++j) {
        int f = f0 + w * 16 + koct * 4 + j;
        if (f < NF) {
            long base = (((long)g * NB + b) * NF + f) * CONDC;
            h_part[base + sel16] = acc0[j];
            h_part[base + 16 + sel16] = acc1[j];
        }
    }
}

__global__ __launch_bounds__(64) void k_params(const float* __restrict__ h_part,
                                               const float* __restrict__ w2,
                                               const float* __restrict__ b1,
                                               const float* __restrict__ b2,
                                               float* __restrict__ par) {
    __shared__ float s_h[CONDC];
    const int f = blockIdx.x;
    const int b = blockIdx.y;
    const int t = threadIdx.x;
    if (t < CONDC) {
        float v = b1[t];
        #pragma unroll
        for (int g = 0; g < 4; ++g)
            v += h_part[(((long)g * NB + b) * NF + f) * CONDC + t];
        s_h[t] = (v >= 0.f) ? v : 0.01f * v;
    }
    __syncthreads();
    float acc = b2[t];
    #pragma unroll 8
    for (int cin = 0; cin < CONDC; ++cin) acc += s_h[cin] * w2[t * CONDC + cin];
    par[((long)b * NF + f) * 64 + t] = tanhf(acc);
}

/* ---- forward DFT of windowed frames; W frags direct from global (verified R10) ---- */
__global__ __launch_bounds__(256) void k_dft_frames2(const float* __restrict__ x,
                                                     const unsigned short* __restrict__ wtab,
                                                     float* __restrict__ X) {
    __shared__ __align__(16) unsigned short s_a[4824];
    const int t = threadIdx.x;
    const int ftile = blockIdx.x;   /* 0..16 */
    const int bi = blockIdx.y;      /* 0..15 */
    const int f0 = ftile * 64;
    const long pos0 = (long)f0 * HOP - 128;
    const int w = t >> 6;
    const int l = t & 63;
    const int sel16 = l & 15;
    const int koct = l >> 4;

    const float* xrow = &x[(long)bi * TT];
    for (int u = t; u < 4288; u += 256) {
        long p = pos0 + u;
        if (p < 0) p = -p;
        if (p >= TT) p = 2 * (TT - 1) - p;
        int off = u + ((u >> 6) << 3);
        s_a[off] = tobf16_rn(xrow[p]);
    }
    __syncthreads();

    const unsigned short* WF = wtab + (l << 3);
    for (int nt = 0; nt < 16; ++nt) {
        f32x4 acc = {0.f, 0.f, 0.f, 0.f};
        #pragma unroll
        for (int ks = 0; ks < 8; ++ks) {
            int u = (w * 16 + sel16) * 64 + ks * 32 + koct * 8;
            int aoff = u + ((u >> 6) << 3);
            bf16x8 ah = *(const bf16x8*)&s_a[aoff];
            bf16x8 bh = *(const bf16x8*)&WF[(nt << 12) + (ks << 9)];
            acc = __builtin_amdgcn_mfma_f32_16x16x32_bf16(ah, bh, acc, 0, 0, 0);
        }
        #pragma unroll
        for (int j = 0; j < 4; ++j) {
            int f = f0 + w * 16 + koct * 4 + j;
            if (f < NF) X[((long)bi * NF + f) * 256 + nt * 16 + sel16] = acc[j];
        }
    }
}

/* ---- FUSED v5: R10 structure, SMALLER tile M=16. 256 thr / 4 waves; wave w
   handles nt = w*4+s. Per-thread filt-build = 16 rows (half of R10). LDS 18.4 KB
   -> 8 blocks/CU = full 32-wave budget. grid (65, 32). ---- */
__global__ __launch_bounds__(256) void k_fused5(const float* __restrict__ par,
                                                const unsigned short* __restrict__ wtab,
                                                const float* __restrict__ X,
                                                float* __restrict__ accb) {
    __shared__ __align__(16) unsigned short s_f[16 * FPAD];   /* 8.4 KB */
    __shared__ __align__(16) unsigned short s_y[16 * FPAD];   /* 8.4 KB */
    __shared__ float s_parl[256];                              /* 1 KB */
    float* s_ola = (float*)s_f;   /* iDFT-phase alias: 1216 f32 < 8.4 KB */

    const int t = threadIdx.x;
    const int ftile = blockIdx.x;   /* 0..64 */
    const int bo = blockIdx.y;      /* 0..31 */
    const int b = bo >> 2;
    const int o = bo & 3;
    const int f0 = ftile * 16;
    const int w = t >> 6;           /* 0..3 = nh */
    const int l = t & 63;
    const int sel16 = l & 15;
    const int koct = l >> 4;

    const float ang = 2.f * PI_F / 256.f;
    const float ta = ((float)t - 128.f) * (1.f / 256.f);
    const float fir = 0.42f - 0.5f * cosf(ang * (float)t) + 0.08f * cosf(2.f * ang * (float)t);
    const float fsc = fir * (1.f / 1024.f);

    const unsigned short* W0 = wtab + 65536 + (l << 3);
    const unsigned short* WI = wtab + 2 * 65536 + (l << 3);

    /* stage par: s_parl[f_r*16 + isel*8 + q] (16 rows x 16) */
    {
        int f_r = t >> 4;
        int idx = t & 15;
        int isel = idx >> 3;
        int q = idx & 7;
        int col = (o * 2 + isel) * 4 + (q & 3) + ((q >> 2) * 32);
        int fc = f0 + f_r;
        if (fc >= NF) fc = NF - 1;
        s_parl[t] = par[((long)b * NF + fc) * 64 + col];
    }

    for (int i = 0; i < 2; ++i) {
        __syncthreads();   /* parl ready / prev-i s_f reads done */
        /* build filt tile: thread owns column k=t, 16 rows */
        for (int r = 0; r < 16; ++r) {
            const float* pp = &s_parl[r * 16 + i * 8];
            float v = (pp[0] * sincpoly(pp[4] * ta + 1e-6f)
                     + pp[1] * sincpoly(pp[5] * ta + 1e-6f)
                     + pp[2] * sincpoly(pp[6] * ta + 1e-6f)
                     + pp[3] * sincpoly(pp[7] * ta + 1e-6f)) * fsc;
            s_f[r * FPAD + t] = tobf16_rn(v);
        }
        __syncthreads();   /* filt ready */
        const long xbase = ((long)(b * 2 + i) * NF) * 256;
        for (int s = 0; s < 4; ++s) {
            const int nt = w * 4 + s;
            f32x4 acc = {0.f, 0.f, 0.f, 0.f};
            #pragma unroll
            for (int ks = 0; ks < 8; ++ks) {
                bf16x8 ah = *(const bf16x8*)&s_f[sel16 * FPAD + ks * 32 + koct * 8];
                bf16x8 bh = *(const bf16x8*)&W0[(nt << 12) + (ks << 9)];
                acc = __builtin_amdgcn_mfma_f32_16x16x32_bf16(ah, bh, acc, 0, 0, 0);
            }
            #pragma unroll
            for (int j = 0; j < 4; ++j) {
                int row = koct * 4 + j;
                int col = nt * 16 + sel16;
                int f = f0 + row;
                float xv = (f < NF) ? X[xbase + (long)f * 256 + col] : 0.f;
                float h = acc[j];
                float p = h * xv;
                float q2 = __shfl_xor(p, 1);
                float r2 = h * __shfl_xor(xv, 1);
                float s2 = __shfl_xor(r2, 1);
                float yv = (sel16 & 1) ? (r2 + s2) : (p - q2);
                if (nt == 0 && sel16 < 2) yv = p;
                int yoff = row * FPAD + col;
                if (i == 0) s_y[yoff] = tobf16_rn(yv);
                else        s_y[yoff] = tobf16_rn(yv + frombf16(s_y[yoff]));
            }
        }
    }

    /* ---- phase 2: inverse DFT from s_y, OLA in LDS ---- */
    __syncthreads();   /* s_y complete; s_f reads done -> alias s_ola */
    for (int u = t; u < 1216; u += 256) s_ola[u] = 0.f;
    __syncthreads();
    for (int s = 0; s < 4; ++s) {
        const int nt = w * 4 + s;
        f32x4 acc = {0.f, 0.f, 0.f, 0.f};
        #pragma unroll
        for (int ks = 0; ks < 8; ++ks) {
            bf16x8 ah = *(const bf16x8*)&s_y[sel16 * FPAD + ks * 32 + koct * 8];
            bf16x8 bh = *(const bf16x8*)&WI[(nt << 12) + (ks << 9)];
            acc = __builtin_amdgcn_mfma_f32_16x16x32_bf16(ah, bh, acc, 0, 0, 0);
        }
        #pragma unroll
        for (int j = 0; j < 4; ++j) {
            int row = koct * 4 + j;
            int n = nt * 16 + sel16;
            atomicAdd(&s_ola[row * 64 + n], acc[j]);
        }
    }
    __syncthreads();
    /* write out: interior [192,1024) exclusive to this block; edges atomic */
    for (int u = t; u < 1216; u += 256) {
        long pos = (long)f0 * HOP + u;
        if (pos < (long)LL) {
            float v = s_ola[u];
            long base = ((long)(b * OUT_CHN + o)) * LL + pos;
            if (u < 192 || u >= 1024) atomicAdd(&accb[base], v);
            else accb[base] = v;
        }
    }
}

__global__ __launch_bounds__(256) void k_norm(const float* __restrict__ accbuf,
                                              const float* __restrict__ bias,
                                              float* __restrict__ out) {
    int idx = blockIdx.x * 256 + threadIdx.x;
    if (idx >= NB * OUT_CHN * TT) return;
    int tpos = idx & (TT - 1);
    int bo = idx >> 16;
    int o = bo & 3;
    int tt = tpos + 128;
    float env;
    if (tt >= 192 && tt < (NF - 1) * HOP) {
        env = 1.5f;   /* interior: sum of 4 overlapping hann^2 at hop=K/4 is exactly 3/2 */
    } else {
        env = 0.f;
        int fhi = tt >> 6;
        #pragma unroll
        for (int d = 0; d < 4; ++d) {
            int f = fhi - d;
            int n = tt - f * HOP;
            if (f >= 0 && f < NF && n >= 0 && n < KK) {
                float angn = (2.f * PI_F / 256.f) * (float)n;
                float wv = 0.5f * (1.f - cosf(angn));
                env += wv * wv;
            }
        }
    }
    out[idx] = accbuf[(long)bo * LL + tt] / env + bias[o];
}

extern "C" void kernel_launch(void* const* d_in, const int* in_sizes, int n_in,
                              void* d_out, int out_size, void* d_ws, size_t ws_size,
                              hipStream_t stream) {
    const float* x    = (const float*)d_in[0];
    const float* cond = (const float*)d_in[1];
    const float* w1   = (const float*)d_in[2];
    const float* b1   = (const float*)d_in[3];
    const float* w2   = (const float*)d_in[4];
    const float* b2   = (const float*)d_in[5];
    const float* bias = (const float*)d_in[6];
    float* out = (float*)d_out;
    float* ws  = (float*)d_ws;
    unsigned short* wtab = (unsigned short*)(ws + WTAB_OFF);
    float* par    = ws + PAR_OFF;
    float* X      = ws + X_OFF;
    float* acc    = ws + ACC_OFF;
    float* h_part = ws + HPART_OFF;

    hipLaunchKernelGGL(k_wsetup, dim3(768), dim3(256), 0, stream, wtab);
    hipLaunchKernelGGL(k_hconv3, dim3(17, 4, NB), dim3(256), 0, stream, cond, w1, h_part);
    hipLaunchKernelGGL(k_params, dim3(NF, NB), dim3(64), 0, stream, h_part, w2, b1, b2, par);
    hipLaunchKernelGGL(k_dft_frames2, dim3(17, 16), dim3(256), 0, stream, x, wtab, X);
    (void)hipMemsetAsync(acc, 0, (size_t)ACC_N * sizeof(float), stream);
    hipLaunchKernelGGL(k_fused5, dim3(65, 32), dim3(256), 0, stream, par, wtab, X, acc);
    hipLaunchKernelGGL(k_norm, dim3(8192), dim3(256), 0, stream, acc, bias, out);
}

// Round 16
// 197.924 us; speedup vs baseline: 2.2346x; 1.1566x over previous
//
#include <hip/hip_runtime.h>
#include <math.h>

#define NB 8
#define IN_CH 2
#define OUT_CHN 4
#define NSINC 4
#define CONDC 32
#define KK 256
#define HOP 64
#define TT 65536
#define NF 1025
#define LL (HOP*(NF-1)+KK)   /* 65792 */
#define PI_F 3.14159265358979323846f

/* ws layout (floats):
   wtab   @ 0       : 98304  (3 bf16 matrices x 65536 ushort, FRAGMENT layout)
   par    @ 98304   : 524800
   X      @ 623104  : 4198400
   acc    @ 4821504 : 2105344
   h_part @ 6926848 : 1049600
   total 7,976,448 floats = 31.9 MB */
#define WTAB_OFF 0
#define PAR_OFF  98304
#define X_OFF    623104
#define ACC_OFF  4821504
#define ACC_N    2105344
#define HPART_OFF 6926848

#define FPAD 264

typedef __attribute__((ext_vector_type(8))) short bf16x8;
typedef __attribute__((ext_vector_type(4))) float f32x4;

__device__ __forceinline__ void splitbf(float v, unsigned short& hi, unsigned short& lo) {
    unsigned bits = __float_as_uint(v);
    hi = (unsigned short)(bits >> 16);
    float r = v - __uint_as_float(bits & 0xffff0000u);
    lo = (unsigned short)(__float_as_uint(r) >> 16);
}

__device__ __forceinline__ unsigned short tobf16_rn(float v) {
    unsigned b = __float_as_uint(v);
    return (unsigned short)((b + 0x7FFFu + ((b >> 16) & 1u)) >> 16);
}

__device__ __forceinline__ float frombf16(unsigned short u) {
    return __uint_as_float(((unsigned)u) << 16);
}

/* sinc(x)=sin(pi x)/(pi x) via Taylor in (pi x)^2; |pi x| <= 1.571 here -> err < 4e-8 */
__device__ __forceinline__ float sincpoly(float x) {
    float y = PI_F * x;
    float y2 = y * y;
    return 1.f + y2 * (-1.6666667e-1f + y2 * (8.3333333e-3f + y2 * (-1.9841270e-4f
              + y2 * (2.7557319e-6f + y2 * (-2.5052108e-8f)))));
}

/* ---- W tables in MFMA B-FRAGMENT layout (verified R10):
   addr = (m<<16) | (nt<<12) | (ks<<9) | (koct<<7) | (sel<<3) | e ---- */
__global__ __launch_bounds__(256) void k_wsetup(unsigned short* __restrict__ wtab) {
    int idx = blockIdx.x * 256 + threadIdx.x;   /* grid 768 */
    int m = idx >> 16;
    int rem = idx & 65535;
    int oc = rem >> 8;
    int kd = rem & 255;
    const float ang = 2.f * PI_F / 256.f;
    float v;
    if (m < 2) {
        if (oc == 0) v = 1.f;
        else if (oc == 1) v = (kd & 1) ? -1.f : 1.f;
        else {
            int nu = oc >> 1;
            float th = ang * (float)((nu * kd) & 255);
            v = (oc & 1) ? -sinf(th) : cosf(th);
        }
        if (m == 0) v *= 0.5f * (1.f - cosf(ang * (float)kd));
    } else {
        float s;
        if (kd == 0) s = 1.f;
        else if (kd == 1) s = (oc & 1) ? -1.f : 1.f;
        else {
            int nu = kd >> 1;
            float th = ang * (float)((nu * oc) & 255);
            s = (kd & 1) ? -2.f * sinf(th) : 2.f * cosf(th);
        }
        v = s * (1.f / 256.f) * 0.5f * (1.f - cosf(ang * (float)oc));
    }
    int nt = oc >> 4, sel = oc & 15;
    int ks = kd >> 5, koct = (kd >> 3) & 3, e = kd & 7;
    wtab[(m << 16) | (nt << 12) | (ks << 9) | (koct << 7) | (sel << 3) | e] = tobf16_rn(v);
}

/* ---- hconv as split-bf16 MFMA GEMM (verified R4, unchanged) ---- */
__global__ __launch_bounds__(256) void k_hconv3(const float* __restrict__ cond,
                                                const float* __restrict__ w1,
                                                float* __restrict__ h_part) {
    __shared__ __align__(16) unsigned short s_a_hi[4824];
    __shared__ __align__(16) unsigned short s_a_lo[4824];
    __shared__ __align__(16) unsigned short s_b_hi[32 * 264];
    __shared__ __align__(16) unsigned short s_b_lo[32 * 264];
    const int t = threadIdx.x;
    const int ftile = blockIdx.x;
    const int g = blockIdx.y;
    const int b = blockIdx.z;
    const int f0 = ftile * 64;
    const long pos0 = (long)f0 * HOP - 128;
    const int w = t >> 6;
    const int l = t & 63;
    const int sel16 = l & 15;
    const int koct = l >> 4;

    f32x4 acc0 = {0.f, 0.f, 0.f, 0.f};
    f32x4 acc1 = {0.f, 0.f, 0.f, 0.f};

    for (int ci = 0; ci < 8; ++ci) {
        const int cin = g * 8 + ci;
        __syncthreads();
        const float* crow = &cond[((long)b * CONDC + cin) * TT];
        for (int u = t; u < 4288; u += 256) {
            long p = pos0 + u;
            if (p < 0) p = -p;
            if (p >= TT) p = 2 * (TT - 1) - p;
            unsigned short hi, lo;
            splitbf(crow[p], hi, lo);
            int off = u + ((u >> 6) << 3);
            s_a_hi[off] = hi;
            s_a_lo[off] = lo;
        }
        for (int m4 = t; m4 < 2048; m4 += 256) {
            int c = m4 >> 6;
            int k4 = (m4 & 63) << 2;
            float4 v = *(const float4*)&w1[((c * CONDC + cin) << 8) + k4];
            ushort4 hi, lo;
            splitbf(v.x, hi.x, lo.x);
            splitbf(v.y, hi.y, lo.y);
            splitbf(v.z, hi.z, lo.z);
            splitbf(v.w, hi.w, lo.w);
            int off = c * 264 + k4;
            *(ushort4*)&s_b_hi[off] = hi;
            *(ushort4*)&s_b_lo[off] = lo;
        }
        __syncthreads();
        const int flocal = w * 16 + sel16;
        #pragma unroll
        for (int ks = 0; ks < 8; ++ks) {
            int u = flocal * 64 + ks * 32 + koct * 8;
            int aoff = u + ((u >> 6) << 3);
            bf16x8 ahi = *(const bf16x8*)&s_a_hi[aoff];
            bf16x8 alo = *(const bf16x8*)&s_a_lo[aoff];
            int boff0 = sel16 * 264 + ks * 32 + koct * 8;
            int boff1 = (16 + sel16) * 264 + ks * 32 + koct * 8;
            bf16x8 b0h = *(const bf16x8*)&s_b_hi[boff0];
            bf16x8 b0l = *(const bf16x8*)&s_b_lo[boff0];
            bf16x8 b1h = *(const bf16x8*)&s_b_hi[boff1];
            bf16x8 b1l = *(const bf16x8*)&s_b_lo[boff1];
            acc0 = __builtin_amdgcn_mfma_f32_16x16x32_bf16(ahi, b0h, acc0, 0, 0, 0);
            acc0 = __builtin_amdgcn_mfma_f32_16x16x32_bf16(alo, b0h, acc0, 0, 0, 0);
            acc0 = __builtin_amdgcn_mfma_f32_16x16x32_bf16(ahi, b0l, acc0, 0, 0, 0);
            acc1 = __builtin_amdgcn_mfma_f32_16x16x32_bf16(ahi, b1h, acc1, 0, 0, 0);
            acc1 = __builtin_amdgcn_mfma_f32_16x16x32_bf16(alo, b1h, acc1, 0, 0, 0);
            acc1 = __builtin_amdgcn_mfma_f32_16x16x32_bf16(ahi, b1l, acc1, 0, 0, 0);
        }
    }

    #pragma unroll
    for (int j = 0; j < 4; ++j) {
        int f = f0 + w * 16 + koct * 4 + j;
        if (f < NF) {
            long base = (((long)g * NB + b) * NF + f) * CONDC;
            h_part[base + sel16] = acc0[j];
            h_part[base + 16 + sel16] = acc1[j];
        }
    }
}

__global__ __launch_bounds__(64) void k_params(const float* __restrict__ h_part,
                                               const float* __restrict__ w2,
                                               const float* __restrict__ b1,
                                               const float* __restrict__ b2,
                                               float* __restrict__ par) {
    __shared__ float s_h[CONDC];
    const int f = blockIdx.x;
    const int b = blockIdx.y;
    const int t = threadIdx.x;
    if (t < CONDC) {
        float v = b1[t];
        #pragma unroll
        for (int g = 0; g < 4; ++g)
            v += h_part[(((long)g * NB + b) * NF + f) * CONDC + t];
        s_h[t] = (v >= 0.f) ? v : 0.01f * v;
    }
    __syncthreads();
    float acc = b2[t];
    #pragma unroll 8
    for (int cin = 0; cin < CONDC; ++cin) acc += s_h[cin] * w2[t * CONDC + cin];
    par[((long)b * NF + f) * 64 + t] = tanhf(acc);
}

/* ---- forward DFT of windowed frames; W frags direct from global (verified R10) ---- */
__global__ __launch_bounds__(256) void k_dft_frames2(const float* __restrict__ x,
                                                     const unsigned short* __restrict__ wtab,
                                                     float* __restrict__ X) {
    __shared__ __align__(16) unsigned short s_a[4824];
    const int t = threadIdx.x;
    const int ftile = blockIdx.x;   /* 0..16 */
    const int bi = blockIdx.y;      /* 0..15 */
    const int f0 = ftile * 64;
    const long pos0 = (long)f0 * HOP - 128;
    const int w = t >> 6;
    const int l = t & 63;
    const int sel16 = l & 15;
    const int koct = l >> 4;

    const float* xrow = &x[(long)bi * TT];
    for (int u = t; u < 4288; u += 256) {
        long p = pos0 + u;
        if (p < 0) p = -p;
        if (p >= TT) p = 2 * (TT - 1) - p;
        int off = u + ((u >> 6) << 3);
        s_a[off] = tobf16_rn(xrow[p]);
    }
    __syncthreads();

    const unsigned short* WF = wtab + (l << 3);
    for (int nt = 0; nt < 16; ++nt) {
        f32x4 acc = {0.f, 0.f, 0.f, 0.f};
        #pragma unroll
        for (int ks = 0; ks < 8; ++ks) {
            int u = (w * 16 + sel16) * 64 + ks * 32 + koct * 8;
            int aoff = u + ((u >> 6) << 3);
            bf16x8 ah = *(const bf16x8*)&s_a[aoff];
            bf16x8 bh = *(const bf16x8*)&WF[(nt << 12) + (ks << 9)];
            acc = __builtin_amdgcn_mfma_f32_16x16x32_bf16(ah, bh, acc, 0, 0, 0);
        }
        #pragma unroll
        for (int j = 0; j < 4; ++j) {
            int f = f0 + w * 16 + koct * 4 + j;
            if (f < NF) X[((long)bi * NF + f) * 256 + nt * 16 + sel16] = acc[j];
        }
    }
}

/* ---- FUSED (R10-verified body): filt DFT + cmul(X) + iDFT + LDS OLA.
   1D grid, XCD-aware decode: idx = o*264 + (ftile*8 + b). Since 264 % 8 == 0,
   idx % 8 == b -> every block of batch b lands on XCD b; X[b] (2.1 MB) becomes
   L2-resident on that XCD, killing the 8x cross-XCD X re-fetch. ---- */
__global__ __launch_bounds__(256) void k_fused(const float* __restrict__ par,
                                               const unsigned short* __restrict__ wtab,
                                               const float* __restrict__ X,
                                               float* __restrict__ accb) {
    __shared__ __align__(16) unsigned short s_f[32 * FPAD];   /* filt tile (one i) */
    __shared__ __align__(16) unsigned short s_y[32 * FPAD];   /* Y bf16 */
    __shared__ float s_parl[512];
    float* s_ola = (float*)s_f;   /* phase-2 alias: 2240 f32 inside 16.9 KB */

    const int idx = blockIdx.x;     /* 0..1055 */
    const int o = idx / 264;
    const int rem = idx - o * 264;
    const int ftile = rem >> 3;     /* 0..32 */
    const int b = rem & 7;
    const int bo = b * 4 + o;       /* acc row */
    const int t = threadIdx.x;
    const int f0 = ftile * 32;
    const int w = t >> 6;
    const int l = t & 63;
    const int sel16 = l & 15;
    const int koct = l >> 4;
    const int rh = w & 1;
    const int nh = w >> 1;       /* 0 or 1 */
    const int flocal = rh * 16 + sel16;

    const float ang = 2.f * PI_F / 256.f;
    const float ta = ((float)t - 128.f) * (1.f / 256.f);
    const float fir = 0.42f - 0.5f * cosf(ang * (float)t) + 0.08f * cosf(2.f * ang * (float)t);
    const float fsc = fir * (1.f / 1024.f);

    const unsigned short* W0 = wtab + 65536 + (l << 3);       /* m=1 lane base */
    const unsigned short* WI = wtab + 2 * 65536 + (l << 3);   /* m=2 lane base */

    /* stage par cooperatively */
    for (int u = t; u < 512; u += 256) {
        int f_r = u >> 4;
        int idx2 = u & 15;
        int isel = idx2 >> 3;
        int q = idx2 & 7;
        int col = (o * 2 + isel) * 4 + (q & 3) + ((q >> 2) * 32);
        int fc = f0 + f_r;
        if (fc >= NF) fc = NF - 1;
        s_parl[u] = par[((long)b * NF + fc) * 64 + col];
    }

    for (int i = 0; i < 2; ++i) {
        __syncthreads();   /* parl ready / prev-i s_f reads done */
        for (int r = 0; r < 32; ++r) {
            const float* pp = &s_parl[r * 16 + i * 8];
            float v = (pp[0] * sincpoly(pp[4] * ta + 1e-6f)
                     + pp[1] * sincpoly(pp[5] * ta + 1e-6f)
                     + pp[2] * sincpoly(pp[6] * ta + 1e-6f)
                     + pp[3] * sincpoly(pp[7] * ta + 1e-6f)) * fsc;
            s_f[r * FPAD + t] = tobf16_rn(v);
        }
        __syncthreads();   /* filt ready */
        const long xbase = ((long)(b * 2 + i) * NF) * 256;
        for (int s = 0; s < 8; ++s) {
            const int nt = nh * 8 + s;
            float xv[4];
            #pragma unroll
            for (int j = 0; j < 4; ++j) {
                int f = f0 + rh * 16 + koct * 4 + j;
                int col = nt * 16 + sel16;
                xv[j] = (f < NF) ? X[xbase + (long)f * 256 + col] : 0.f;
            }
            f32x4 acc = {0.f, 0.f, 0.f, 0.f};
            #pragma unroll
            for (int ks = 0; ks < 8; ++ks) {
                bf16x8 ah = *(const bf16x8*)&s_f[flocal * FPAD + ks * 32 + koct * 8];
                bf16x8 bh = *(const bf16x8*)&W0[(nt << 12) + (ks << 9)];
                acc = __builtin_amdgcn_mfma_f32_16x16x32_bf16(ah, bh, acc, 0, 0, 0);
            }
            #pragma unroll
            for (int j = 0; j < 4; ++j) {
                int row = rh * 16 + koct * 4 + j;
                int col = nt * 16 + sel16;
                float h = acc[j];
                float p = h * xv[j];
                float q2 = __shfl_xor(p, 1);
                float r2 = h * __shfl_xor(xv[j], 1);
                float s2 = __shfl_xor(r2, 1);
                float yv = (sel16 & 1) ? (r2 + s2) : (p - q2);
                if (nt == 0 && sel16 < 2) yv = p;
                int yoff = row * FPAD + col;
                if (i == 0) s_y[yoff] = tobf16_rn(yv);
                else        s_y[yoff] = tobf16_rn(yv + frombf16(s_y[yoff]));
            }
        }
    }

    /* ---- phase 2: inverse DFT from s_y, OLA in LDS ---- */
    __syncthreads();   /* s_y complete; s_f reads done -> alias as s_ola */
    for (int u = t; u < 2240; u += 256) s_ola[u] = 0.f;
    __syncthreads();
    for (int s = 0; s < 8; ++s) {
        const int nt = nh * 8 + s;
        f32x4 acc = {0.f, 0.f, 0.f, 0.f};
        #pragma unroll
        for (int ks = 0; ks < 8; ++ks) {
            bf16x8 ah = *(const bf16x8*)&s_y[flocal * FPAD + ks * 32 + koct * 8];
            bf16x8 bh = *(const bf16x8*)&WI[(nt << 12) + (ks << 9)];
            acc = __builtin_amdgcn_mfma_f32_16x16x32_bf16(ah, bh, acc, 0, 0, 0);
        }
        #pragma unroll
        for (int j = 0; j < 4; ++j) {
            int row = rh * 16 + koct * 4 + j;
            int n = nt * 16 + sel16;
            atomicAdd(&s_ola[row * 64 + n], acc[j]);
        }
    }
    __syncthreads();
    for (int u = t; u < 2240; u += 256) {
        long pos = (long)f0 * HOP + u;
        if (pos < (long)LL) {
            float v = s_ola[u];
            long base = (long)bo * LL + pos;
            if (u < 192 || u >= 2048) atomicAdd(&accb[base], v);
            else accb[base] = v;
        }
    }
}

__global__ __launch_bounds__(256) void k_norm(const float* __restrict__ accbuf,
                                              const float* __restrict__ bias,
                                              float* __restrict__ out) {
    int idx = blockIdx.x * 256 + threadIdx.x;
    if (idx >= NB * OUT_CHN * TT) return;
    int tpos = idx & (TT - 1);
    int bo = idx >> 16;
    int o = bo & 3;
    int tt = tpos + 128;
    float env;
    if (tt >= 192 && tt < (NF - 1) * HOP) {
        env = 1.5f;   /* interior: sum of 4 overlapping hann^2 at hop=K/4 is exactly 3/2 */
    } else {
        env = 0.f;
        int fhi = tt >> 6;
        #pragma unroll
        for (int d = 0; d < 4; ++d) {
            int f = fhi - d;
            int n = tt - f * HOP;
            if (f >= 0 && f < NF && n >= 0 && n < KK) {
                float angn = (2.f * PI_F / 256.f) * (float)n;
                float wv = 0.5f * (1.f - cosf(angn));
                env += wv * wv;
            }
        }
    }
    out[idx] = accbuf[(long)bo * LL + tt] / env + bias[o];
}

extern "C" void kernel_launch(void* const* d_in, const int* in_sizes, int n_in,
                              void* d_out, int out_size, void* d_ws, size_t ws_size,
                              hipStream_t stream) {
    const float* x    = (const float*)d_in[0];
    const float* cond = (const float*)d_in[1];
    const float* w1   = (const float*)d_in[2];
    const float* b1   = (const float*)d_in[3];
    const float* w2   = (const float*)d_in[4];
    const float* b2   = (const float*)d_in[5];
    const float* bias = (const float*)d_in[6];
    float* out = (float*)d_out;
    float* ws  = (float*)d_ws;
    unsigned short* wtab = (unsigned short*)(ws + WTAB_OFF);
    float* par    = ws + PAR_OFF;
    float* X      = ws + X_OFF;
    float* acc    = ws + ACC_OFF;
    float* h_part = ws + HPART_OFF;

    hipLaunchKernelGGL(k_wsetup, dim3(768), dim3(256), 0, stream, wtab);
    hipLaunchKernelGGL(k_hconv3, dim3(17, 4, NB), dim3(256), 0, stream, cond, w1, h_part);
    hipLaunchKernelGGL(k_params, dim3(NF, NB), dim3(64), 0, stream, h_part, w2, b1, b2, par);
    hipLaunchKernelGGL(k_dft_frames2, dim3(17, 16), dim3(256), 0, stream, x, wtab, X);
    (void)hipMemsetAsync(acc, 0, (size_t)ACC_N * sizeof(float), stream);
    hipLaunchKernelGGL(k_fused, dim3(1056), dim3(256), 0, stream, par, wtab, X, acc);
    hipLaunchKernelGGL(k_norm, dim3(8192), dim3(256), 0, stream, acc, bias, out);
}